// Round 13
// baseline (726.309 us; speedup 1.0000x reference)
//
#include <hip/hip_runtime.h>
#include <hip/hip_bf16.h>
#include <stdint.h>

// dMaSIFConv — R13: register diet to cross the 64-reg occupancy step
// (m69: waves/SIMD = 8 iff total regs <= 64). R12: arch 40 + acc ~24-30 ->
// (64,128] bucket -> 4 waves/SIMD (53%), VALUBusy 77%.
// Changes: (1) f staged via global_load_lds width=16 (kills the two float4
// staging registers held across a barrier + staging VALU); gn_apply writes f
// pre-padded in per-chunk 68-float-row tiles so contiguity + bank padding
// coexist. (2) kg pointer-select hoisted: zero slot lives at hcA[..][jt][32],
// per-lane idx computed once. 4 blocks/CU x 8 waves = 32 waves = HW cap;
// grid 1024 = single pass, zero tail.
// N=8192, I=16, H=O=64, CUTS=8, GROUPS=4. Wire dtype bf16 (detect kept).

#define N_PTS   8192
#define CHUNK   64
#define NCHUNK  (N_PTS / CHUNK)
#define WPB     8                       // waves per conv block
#define PSCALE  0.07856742013183861f    // 1/(sqrt(2)*9)
#define GN_CNT  (N_PTS * 16)
#define FS_STRIDE 68                    // padded f row stride (floats)
#define CHUNK_FLOATS (CHUNK * FS_STRIDE)   // 4352 floats = 17408 B

// fp32 pool offsets (prefix sums of input element counts)
#define OFF_POINTS 0
#define OFF_NUV    24576
#define OFF_FEAT   98304
#define OFF_WIN1   229376
#define OFF_BIN1   230400
#define OFF_WIN2   230464
#define OFF_BIN2   234560
#define OFF_GNIW   234624
#define OFF_GNIB   234688
#define OFF_A1     234752
#define OFF_B1     234776
#define OFF_A2     234784
#define OFF_B2     235296
#define OFF_WOUT1  235360
#define OFF_BOUT1  239456
#define OFF_WOUT2  239520
#define OFF_BOUT2  243616
#define OFF_GNOW   243680
#define OFF_GNOB   243744
#define CVT_TOTAL  243808
#define NSEG 19

typedef _Float16 half2_t __attribute__((ext_vector_type(2)));
typedef _Float16 f16x8   __attribute__((ext_vector_type(8)));
typedef float    f32x4   __attribute__((ext_vector_type(4)));
typedef __attribute__((address_space(3))) uint32_t lds_u32_t;
typedef __attribute__((address_space(1))) const uint32_t glb_u32_t;

struct InPtrs { const void* p[NSEG]; };

__device__ __forceinline__ float rfl(float x) {
  return __int_as_float(__builtin_amdgcn_readfirstlane(__float_as_int(x)));
}
__device__ __forceinline__ float leaky(float x) { return x > 0.f ? x : 0.2f * x; }

#if __has_builtin(__builtin_amdgcn_cvt_pkrtz)
__device__ __forceinline__ half2_t pk16(float a, float b) {
  return __builtin_bit_cast(half2_t, __builtin_amdgcn_cvt_pkrtz(a, b));
}
#else
__device__ __forceinline__ half2_t pk16(float a, float b) {
  half2_t r; r.x = (_Float16)a; r.y = (_Float16)b; return r;
}
#endif

// ---------------- prep: detect dtype, convert all inputs to fp32 pool -------
__global__ __launch_bounds__(256) void prep_kernel(InPtrs ptrs, float* dst,
                                                   float* gstats) {
  if (blockIdx.x == 0 && threadIdx.x < 16) gstats[threadIdx.x] = 0.f;
  const uint32_t w0 = ((const uint32_t*)ptrs.p[7])[0];   // gn_in_w (all ones)
  const bool bf = (w0 != 0x3F800000u);
  const int CUM[NSEG + 1] = {0, 24576, 98304, 229376, 230400, 230464, 234560,
                             234624, 234688, 234752, 234776, 234784, 235296,
                             235360, 239456, 239520, 243616, 243680, 243744,
                             243808};
  for (int e = blockIdx.x * 256 + threadIdx.x; e < CVT_TOTAL;
       e += gridDim.x * 256) {
    int s = 0;
#pragma unroll
    for (int i = 1; i < NSEG; ++i) s += (e >= CUM[i]) ? 1 : 0;
    const int rem = e - CUM[s];
    float v = bf ? __bfloat162float(((const __hip_bfloat16*)ptrs.p[s])[rem])
                 : ((const float*)ptrs.p[s])[rem];
    if (s == 0) v *= PSCALE;
    dst[e] = v;
  }
}

// ---------------- input MLP (fp32 pool, float4 loads) -----------------------
__global__ __launch_bounds__(256) void mlp_in_kernel(
    const float* __restrict__ pool, float* __restrict__ fbuf) {
  __shared__ float ls[4][64];
  const int t = threadIdx.x, nl = t >> 6, h = t & 63;
  const int n = blockIdx.x * 4 + nl;
  const float4* fr = (const float4*)(pool + OFF_FEAT + n * 16);
  const float4* w1 = (const float4*)(pool + OFF_WIN1 + h * 16);
  float a = pool[OFF_BIN1 + h];
#pragma unroll
  for (int k = 0; k < 4; ++k) {
    const float4 x = fr[k], w = w1[k];
    a = fmaf(x.x, w.x, a); a = fmaf(x.y, w.y, a);
    a = fmaf(x.z, w.z, a); a = fmaf(x.w, w.w, a);
  }
  ls[nl][h] = leaky(a);
  __syncthreads();
  const float4* w2 = (const float4*)(pool + OFF_WIN2 + h * 64);
  const float4* lr = (const float4*)&ls[nl][0];
  float c = pool[OFF_BIN2 + h];
#pragma unroll
  for (int k = 0; k < 16; ++k) {
    const float4 x = lr[k], w = w2[k];
    c = fmaf(x.x, w.x, c); c = fmaf(x.y, w.y, c);
    c = fmaf(x.z, w.z, c); c = fmaf(x.w, w.w, c);
  }
  fbuf[n * 64 + h] = leaky(c);
}

// ---------------- output MLP (fp32 cbuf input) ------------------------------
__global__ __launch_bounds__(256) void mlp_out_kernel(
    const float* __restrict__ cbuf, const float* __restrict__ pool,
    float* __restrict__ obuf) {
  __shared__ float ls[4][64];
  const int t = threadIdx.x, nl = t >> 6, h = t & 63;
  const int n = blockIdx.x * 4 + nl;
  const float4* cr = (const float4*)(cbuf + n * 64);
  const float4* w1 = (const float4*)(pool + OFF_WOUT1 + h * 64);
  float a = pool[OFF_BOUT1 + h];
#pragma unroll
  for (int k = 0; k < 16; ++k) {
    const float4 x = cr[k], w = w1[k];
    a = fmaf(x.x, w.x, a); a = fmaf(x.y, w.y, a);
    a = fmaf(x.z, w.z, a); a = fmaf(x.w, w.w, a);
  }
  ls[nl][h] = leaky(a);
  __syncthreads();
  const float4* w2 = (const float4*)(pool + OFF_WOUT2 + h * 64);
  const float4* lr = (const float4*)&ls[nl][0];
  float c = pool[OFF_BOUT2 + h];
#pragma unroll
  for (int k = 0; k < 16; ++k) {
    const float4 x = lr[k], w = w2[k];
    c = fmaf(x.x, w.x, c); c = fmaf(x.y, w.y, c);
    c = fmaf(x.z, w.z, c); c = fmaf(x.w, w.w, c);
  }
  obuf[n * 64 + h] = leaky(c);
}

// ---------------- GN stats: 64 blocks, LDS + global atomics -----------------
__global__ __launch_bounds__(256) void gn_stats_kernel(
    const float* __restrict__ buf, float* __restrict__ gstats) {
  __shared__ float red[8];
  const int t = threadIdx.x;
  const int g = (t & 63) >> 4;
  if (t < 8) red[t] = 0.f;
  float s = 0.f, q = 0.f;
  for (int idx = blockIdx.x * 256 + t; idx < N_PTS * 64; idx += 64 * 256) {
    const float v = buf[idx];
    s += v; q = fmaf(v, v, q);
  }
  __syncthreads();
  atomicAdd(&red[g], s);
  atomicAdd(&red[4 + g], q);
  __syncthreads();
  if (t < 8) atomicAdd(&gstats[t], red[t]);
}

// ---------------- GN apply -> padded per-chunk tile layout ------------------
// dst[(n>>6)*4352 + (n&63)*68 + h] so conv can stage with global_load_lds
// (contiguous 17408 B per chunk) while keeping the 68-float bank padding.
__global__ __launch_bounds__(256) void gn_apply_pad_kernel(
    const float* __restrict__ buf, const float* __restrict__ gstats,
    const float* __restrict__ pool, float* __restrict__ fpad) {
  const int idx = blockIdx.x * 256 + threadIdx.x;
  const int h = idx & 63, n = idx >> 6, g = h >> 4;
  const float m = gstats[g] * (1.f / GN_CNT);
  const float v = gstats[4 + g] * (1.f / GN_CNT) - m * m;
  const float rs = rsqrtf(fmaxf(v, 0.f) + 1e-5f);
  const float r = fmaf((buf[idx] - m) * rs, pool[OFF_GNIW + h], pool[OFF_GNIB + h]);
  fpad[(n >> 6) * CHUNK_FLOATS + (n & 63) * FS_STRIDE + h] = r;
}

// ---------------- GN apply + final store (dtype-branched) -------------------
__global__ __launch_bounds__(256) void gn_apply_out_kernel(
    const float* __restrict__ buf, const float* __restrict__ gstats,
    const float* __restrict__ pool, void* __restrict__ out,
    const uint32_t* __restrict__ dref) {
  const bool bf = (dref[0] != 0x3F800000u);
  const int idx = blockIdx.x * 256 + threadIdx.x;
  const int h = idx & 63, g = h >> 4;
  const float m = gstats[g] * (1.f / GN_CNT);
  const float v = gstats[4 + g] * (1.f / GN_CNT) - m * m;
  const float rs = rsqrtf(fmaxf(v, 0.f) + 1e-5f);
  const float r = fmaf((buf[idx] - m) * rs, pool[OFF_GNOW + h], pool[OFF_GNOB + h]);
  if (bf) ((__hip_bfloat16*)out)[idx] = __float2bfloat16(r);
  else    ((float*)out)[idx] = r;
}

// ---------------- O(N^2) conv, 16x16x32 MFMA phase-2 ------------------------
// 8 waves/block, 1024 blocks (4 blocks/CU = 32 waves = cap, single pass).
// phase 1: lane j computes w_j, hc'[c]=w*relu(hc) -> f16 A-fragment rows in
//   per-wave LDS (kg0 b128; kg1 word0 = w; zero slot 32 pre-zeroed once).
// phase 2: 4 jt x 4 ht mfma_f32_16x16x32_f16; epilogue 4x {ds_read f +
//   max + fma} per tile. f staged by global_load_lds (width 16, async).
__global__ __launch_bounds__(512) void conv_kernel(
    const float* __restrict__ pool, const float* __restrict__ fpad,
    float* __restrict__ cbuf) {
  __shared__ float  f_s[CHUNK_FLOATS];       // 17408 B padded f-tile
  __shared__ float4 hcA[WPB][4][33];         // 16.9 KB A-frags + zero slot 32

  const int t = threadIdx.x;
  const int wv = t >> 6, lane = t & 63;
  const int b = blockIdx.x * WPB + wv;
  const int kg  = lane >> 4;                 // k-group: k = 8*kg + i
  const int l15 = lane & 15;
  const int idx_fp = (kg < 2) ? (kg * 16 + l15) : 32;  // A-frag read slot

  // wave-uniform query data -> SGPRs
  const float pbx = rfl(pool[OFF_POINTS + b * 3 + 0]);
  const float pby = rfl(pool[OFF_POINTS + b * 3 + 1]);
  const float pbz = rfl(pool[OFF_POINTS + b * 3 + 2]);
  float nb[9];
#pragma unroll
  for (int i = 0; i < 9; ++i) nb[i] = rfl(pool[OFF_NUV + b * 9 + i]);
  float a1v[24], b1v[8];
#pragma unroll
  for (int i = 0; i < 24; ++i) a1v[i] = rfl(pool[OFF_A1 + i]);
#pragma unroll
  for (int i = 0; i < 8; ++i)  b1v[i] = rfl(pool[OFF_B1 + i]);

  // B fragments: B[k][h] = A2[h][k] (k<8), B2[h] (k==8), 0 (k>8).
  f16x8 bfrag[4];
#pragma unroll
  for (int ht = 0; ht < 4; ++ht) {
    const int h = 16 * ht + l15;
#pragma unroll
    for (int i = 0; i < 8; ++i) {
      float v = 0.f;
      if (kg == 0) v = pool[OFF_A2 + h * 8 + i];
      else if (kg == 1 && i == 0) v = pool[OFF_B2 + h];
      bfrag[ht][i] = (_Float16)v;
    }
  }

  // pre-zero kg1 words 1..3 and the zero slot (index 16..32 of each tile)
  if (lane < 17) {
    float4 z4; z4.x = 0.f; z4.y = 0.f; z4.z = 0.f; z4.w = 0.f;
#pragma unroll
    for (int jt = 0; jt < 4; ++jt) hcA[wv][jt][16 + lane] = z4;
  }

  const f32x4 kzero = {0.f, 0.f, 0.f, 0.f};
  float acc[4] = {0.f, 0.f, 0.f, 0.f};

  for (int c = 0; c < NCHUNK; ++c) {
    // phase-1 inputs for this lane's n
    const int n = c * CHUNK + lane;
    const float px = pool[OFF_POINTS + n * 3 + 0];
    const float py = pool[OFF_POINTS + n * 3 + 1];
    const float pz = pool[OFF_POINTS + n * 3 + 2];
    const float nx = pool[OFF_NUV + n * 9 + 0];
    const float ny = pool[OFF_NUV + n * 9 + 1];
    const float nz = pool[OFF_NUV + n * 9 + 2];

    __syncthreads();                     // prior chunk's LDS reads done

    // async stage this chunk's padded f-tile (17408 B): 1088 float4 total
    {
      const glb_u32_t* src = (const glb_u32_t*)(fpad + c * CHUNK_FLOATS);
      lds_u32_t* dst = (lds_u32_t*)f_s;
      __builtin_amdgcn_global_load_lds(src + t * 4, dst + t * 4, 16, 0, 0);
      __builtin_amdgcn_global_load_lds(src + 2048 + t * 4, dst + 2048 + t * 4,
                                       16, 0, 0);
      if (wv == 0)
        __builtin_amdgcn_global_load_lds(src + 4096 + lane * 4,
                                         dst + 4096 + lane * 4, 16, 0, 0);
    }

    // phase 1: row j = lane of Hc' = [w*relu(hc)[0..7], w, 0...]
    const float dx = px - pbx, dy = py - pby, dz = pz - pbz;
    const float X0 = fmaf(nb[0], dx, fmaf(nb[1], dy, nb[2] * dz));
    const float X1 = fmaf(nb[3], dx, fmaf(nb[4], dy, nb[5] * dz));
    const float X2 = fmaf(nb[6], dx, fmaf(nb[7], dy, nb[8] * dz));
    const float dn = fmaf(nb[0], nx, fmaf(nb[1], ny, nb[2] * nz));
    const float dd = fmaf(dx, dx, fmaf(dy, dy, dz * dz));
    const float tt = 2.f - dn;
    const float w = __expf(-dd * tt * tt);

    float hc[8];
#pragma unroll
    for (int cc = 0; cc < 8; ++cc)
      hc[cc] = w * fmaxf(fmaf(X0, a1v[cc * 3 + 0],
                         fmaf(X1, a1v[cc * 3 + 1],
                         fmaf(X2, a1v[cc * 3 + 2], b1v[cc]))), 0.f);
    float4 lo;
    lo.x = __builtin_bit_cast(float, pk16(hc[0], hc[1]));
    lo.y = __builtin_bit_cast(float, pk16(hc[2], hc[3]));
    lo.z = __builtin_bit_cast(float, pk16(hc[4], hc[5]));
    lo.w = __builtin_bit_cast(float, pk16(hc[6], hc[7]));
    hcA[wv][lane >> 4][l15] = lo;                       // kg0 (k 0..7)
    ((float*)&hcA[wv][lane >> 4][16 + l15])[0] =
        __builtin_bit_cast(float, pk16(w, 0.f));        // kg1 word0 (k8 = w)

    __syncthreads();                     // f_s (vmcnt drained) + hcA visible

    // phase 2: 4 jt x 4 ht tiles
#pragma unroll
    for (int jt = 0; jt < 4; ++jt) {
      const f16x8 af = __builtin_bit_cast(f16x8, hcA[wv][jt][idx_fp]);
      const int fbase = (16 * jt + kg * 4) * FS_STRIDE + l15;
#pragma unroll
      for (int ht = 0; ht < 4; ++ht) {
        const f32x4 D = __builtin_amdgcn_mfma_f32_16x16x32_f16(
            af, bfrag[ht], kzero, 0, 0, 0);
        const float* fb = &f_s[fbase + 16 * ht];
#pragma unroll
        for (int r = 0; r < 4; ++r)
          acc[ht] = fmaf(fb[r * FS_STRIDE], fmaxf(D[r], 0.f), acc[ht]);
      }
    }
  }

  // each col's sum is spread over the 4 lane quads: reduce, lanes 0..15 store
#pragma unroll
  for (int ht = 0; ht < 4; ++ht) {
    acc[ht] += __shfl_xor(acc[ht], 16, 64);
    acc[ht] += __shfl_xor(acc[ht], 32, 64);
  }
  if (lane < 16) {
#pragma unroll
    for (int ht = 0; ht < 4; ++ht)
      cbuf[b * 64 + 16 * ht + lane] = acc[ht];
  }
}

extern "C" void kernel_launch(void* const* d_in, const int* in_sizes, int n_in,
                              void* d_out, int out_size, void* d_ws, size_t ws_size,
                              hipStream_t stream) {
  (void)in_sizes; (void)n_in; (void)out_size; (void)ws_size;
  const uint32_t* dref = (const uint32_t*)d_in[7];   // gn_in_w, all-ones

  float* pool   = (float*)d_ws;               // CVT_TOTAL fp32 inputs
  float* fbuf   = pool + CVT_TOTAL;           // N*64 (pre-GN f / f2-pre)
  float* fpad   = fbuf + N_PTS * 64;          // 128 * 4352 padded f tiles
  float* cbuf   = fpad + NCHUNK * CHUNK_FLOATS;  // N*64 conv output
  float* gstats = cbuf + N_PTS * 64;          // 16 (in:0-7, out:8-15)

  InPtrs ptrs;
  for (int i = 0; i < NSEG; ++i) ptrs.p[i] = d_in[i];

  prep_kernel<<<256, 256, 0, stream>>>(ptrs, pool, gstats);
  mlp_in_kernel<<<N_PTS / 4, 256, 0, stream>>>(pool, fbuf);
  gn_stats_kernel<<<64, 256, 0, stream>>>(fbuf, gstats);
  gn_apply_pad_kernel<<<N_PTS * 64 / 256, 256, 0, stream>>>(fbuf, gstats, pool,
                                                            fpad);
  conv_kernel<<<N_PTS / WPB, 512, 0, stream>>>(pool, fpad, cbuf);
  mlp_out_kernel<<<N_PTS / 4, 256, 0, stream>>>(cbuf, pool, fbuf);
  gn_stats_kernel<<<64, 256, 0, stream>>>(fbuf, gstats + 8);
  gn_apply_out_kernel<<<N_PTS * 64 / 256, 256, 0, stream>>>(
      fbuf, gstats + 8, pool, d_out, dref);
}

// Round 14
// 703.154 us; speedup vs baseline: 1.0329x; 1.0329x over previous
//
#include <hip/hip_runtime.h>
#include <hip/hip_bf16.h>
#include <stdint.h>

// dMaSIFConv — R14: 2 queries per wave (b and b+4096).
// R12/R13 evidence: busy-cyc/wave-chunk pinned at ~1200 across variants;
// per-chunk shared costs (f ds_reads, staging, barriers, loop overhead)
// dominate. Serving 2 queries amortizes all shared costs: wave-chunks
// halve, per-chunk adds only the second query's phase-1 + epilogue VALU
// + 16 MFMAs on the 19%-utilized matrix pipe.
// Grid 512 = 2 blocks/CU exactly; LDS 51.2 KB (3 fit). Layouts unchanged.
// N=8192, I=16, H=O=64, CUTS=8, GROUPS=4. Wire dtype bf16 (detect kept).

#define N_PTS   8192
#define CHUNK   64
#define NCHUNK  (N_PTS / CHUNK)
#define WPB     8                       // waves per conv block
#define PSCALE  0.07856742013183861f    // 1/(sqrt(2)*9)
#define GN_CNT  (N_PTS * 16)
#define FS_STRIDE 68                    // padded f row stride (floats)
#define CHUNK_FLOATS (CHUNK * FS_STRIDE)   // 4352 floats = 17408 B

// fp32 pool offsets (prefix sums of input element counts)
#define OFF_POINTS 0
#define OFF_NUV    24576
#define OFF_FEAT   98304
#define OFF_WIN1   229376
#define OFF_BIN1   230400
#define OFF_WIN2   230464
#define OFF_BIN2   234560
#define OFF_GNIW   234624
#define OFF_GNIB   234688
#define OFF_A1     234752
#define OFF_B1     234776
#define OFF_A2     234784
#define OFF_B2     235296
#define OFF_WOUT1  235360
#define OFF_BOUT1  239456
#define OFF_WOUT2  239520
#define OFF_BOUT2  243616
#define OFF_GNOW   243680
#define OFF_GNOB   243744
#define CVT_TOTAL  243808
#define NSEG 19

typedef _Float16 half2_t __attribute__((ext_vector_type(2)));
typedef _Float16 f16x8   __attribute__((ext_vector_type(8)));
typedef float    f32x4   __attribute__((ext_vector_type(4)));
typedef __attribute__((address_space(3))) uint32_t lds_u32_t;
typedef __attribute__((address_space(1))) const uint32_t glb_u32_t;

struct InPtrs { const void* p[NSEG]; };

__device__ __forceinline__ float rfl(float x) {
  return __int_as_float(__builtin_amdgcn_readfirstlane(__float_as_int(x)));
}
__device__ __forceinline__ float leaky(float x) { return x > 0.f ? x : 0.2f * x; }

#if __has_builtin(__builtin_amdgcn_cvt_pkrtz)
__device__ __forceinline__ half2_t pk16(float a, float b) {
  return __builtin_bit_cast(half2_t, __builtin_amdgcn_cvt_pkrtz(a, b));
}
#else
__device__ __forceinline__ half2_t pk16(float a, float b) {
  half2_t r; r.x = (_Float16)a; r.y = (_Float16)b; return r;
}
#endif

// ---------------- prep: detect dtype, convert all inputs to fp32 pool -------
__global__ __launch_bounds__(256) void prep_kernel(InPtrs ptrs, float* dst,
                                                   float* gstats) {
  if (blockIdx.x == 0 && threadIdx.x < 16) gstats[threadIdx.x] = 0.f;
  const uint32_t w0 = ((const uint32_t*)ptrs.p[7])[0];   // gn_in_w (all ones)
  const bool bf = (w0 != 0x3F800000u);
  const int CUM[NSEG + 1] = {0, 24576, 98304, 229376, 230400, 230464, 234560,
                             234624, 234688, 234752, 234776, 234784, 235296,
                             235360, 239456, 239520, 243616, 243680, 243744,
                             243808};
  for (int e = blockIdx.x * 256 + threadIdx.x; e < CVT_TOTAL;
       e += gridDim.x * 256) {
    int s = 0;
#pragma unroll
    for (int i = 1; i < NSEG; ++i) s += (e >= CUM[i]) ? 1 : 0;
    const int rem = e - CUM[s];
    float v = bf ? __bfloat162float(((const __hip_bfloat16*)ptrs.p[s])[rem])
                 : ((const float*)ptrs.p[s])[rem];
    if (s == 0) v *= PSCALE;
    dst[e] = v;
  }
}

// ---------------- input MLP (fp32 pool, float4 loads) -----------------------
__global__ __launch_bounds__(256) void mlp_in_kernel(
    const float* __restrict__ pool, float* __restrict__ fbuf) {
  __shared__ float ls[4][64];
  const int t = threadIdx.x, nl = t >> 6, h = t & 63;
  const int n = blockIdx.x * 4 + nl;
  const float4* fr = (const float4*)(pool + OFF_FEAT + n * 16);
  const float4* w1 = (const float4*)(pool + OFF_WIN1 + h * 16);
  float a = pool[OFF_BIN1 + h];
#pragma unroll
  for (int k = 0; k < 4; ++k) {
    const float4 x = fr[k], w = w1[k];
    a = fmaf(x.x, w.x, a); a = fmaf(x.y, w.y, a);
    a = fmaf(x.z, w.z, a); a = fmaf(x.w, w.w, a);
  }
  ls[nl][h] = leaky(a);
  __syncthreads();
  const float4* w2 = (const float4*)(pool + OFF_WIN2 + h * 64);
  const float4* lr = (const float4*)&ls[nl][0];
  float c = pool[OFF_BIN2 + h];
#pragma unroll
  for (int k = 0; k < 16; ++k) {
    const float4 x = lr[k], w = w2[k];
    c = fmaf(x.x, w.x, c); c = fmaf(x.y, w.y, c);
    c = fmaf(x.z, w.z, c); c = fmaf(x.w, w.w, c);
  }
  fbuf[n * 64 + h] = leaky(c);
}

// ---------------- output MLP (fp32 cbuf input) ------------------------------
__global__ __launch_bounds__(256) void mlp_out_kernel(
    const float* __restrict__ cbuf, const float* __restrict__ pool,
    float* __restrict__ obuf) {
  __shared__ float ls[4][64];
  const int t = threadIdx.x, nl = t >> 6, h = t & 63;
  const int n = blockIdx.x * 4 + nl;
  const float4* cr = (const float4*)(cbuf + n * 64);
  const float4* w1 = (const float4*)(pool + OFF_WOUT1 + h * 64);
  float a = pool[OFF_BOUT1 + h];
#pragma unroll
  for (int k = 0; k < 16; ++k) {
    const float4 x = cr[k], w = w1[k];
    a = fmaf(x.x, w.x, a); a = fmaf(x.y, w.y, a);
    a = fmaf(x.z, w.z, a); a = fmaf(x.w, w.w, a);
  }
  ls[nl][h] = leaky(a);
  __syncthreads();
  const float4* w2 = (const float4*)(pool + OFF_WOUT2 + h * 64);
  const float4* lr = (const float4*)&ls[nl][0];
  float c = pool[OFF_BOUT2 + h];
#pragma unroll
  for (int k = 0; k < 16; ++k) {
    const float4 x = lr[k], w = w2[k];
    c = fmaf(x.x, w.x, c); c = fmaf(x.y, w.y, c);
    c = fmaf(x.z, w.z, c); c = fmaf(x.w, w.w, c);
  }
  obuf[n * 64 + h] = leaky(c);
}

// ---------------- GN stats: 64 blocks, LDS + global atomics -----------------
__global__ __launch_bounds__(256) void gn_stats_kernel(
    const float* __restrict__ buf, float* __restrict__ gstats) {
  __shared__ float red[8];
  const int t = threadIdx.x;
  const int g = (t & 63) >> 4;
  if (t < 8) red[t] = 0.f;
  float s = 0.f, q = 0.f;
  for (int idx = blockIdx.x * 256 + t; idx < N_PTS * 64; idx += 64 * 256) {
    const float v = buf[idx];
    s += v; q = fmaf(v, v, q);
  }
  __syncthreads();
  atomicAdd(&red[g], s);
  atomicAdd(&red[4 + g], q);
  __syncthreads();
  if (t < 8) atomicAdd(&gstats[t], red[t]);
}

// ---------------- GN apply -> padded per-chunk tile layout ------------------
__global__ __launch_bounds__(256) void gn_apply_pad_kernel(
    const float* __restrict__ buf, const float* __restrict__ gstats,
    const float* __restrict__ pool, float* __restrict__ fpad) {
  const int idx = blockIdx.x * 256 + threadIdx.x;
  const int h = idx & 63, n = idx >> 6, g = h >> 4;
  const float m = gstats[g] * (1.f / GN_CNT);
  const float v = gstats[4 + g] * (1.f / GN_CNT) - m * m;
  const float rs = rsqrtf(fmaxf(v, 0.f) + 1e-5f);
  const float r = fmaf((buf[idx] - m) * rs, pool[OFF_GNIW + h], pool[OFF_GNIB + h]);
  fpad[(n >> 6) * CHUNK_FLOATS + (n & 63) * FS_STRIDE + h] = r;
}

// ---------------- GN apply + final store (dtype-branched) -------------------
__global__ __launch_bounds__(256) void gn_apply_out_kernel(
    const float* __restrict__ buf, const float* __restrict__ gstats,
    const float* __restrict__ pool, void* __restrict__ out,
    const uint32_t* __restrict__ dref) {
  const bool bf = (dref[0] != 0x3F800000u);
  const int idx = blockIdx.x * 256 + threadIdx.x;
  const int h = idx & 63, g = h >> 4;
  const float m = gstats[g] * (1.f / GN_CNT);
  const float v = gstats[4 + g] * (1.f / GN_CNT) - m * m;
  const float rs = rsqrtf(fmaxf(v, 0.f) + 1e-5f);
  const float r = fmaf((buf[idx] - m) * rs, pool[OFF_GNOW + h], pool[OFF_GNOB + h]);
  if (bf) ((__hip_bfloat16*)out)[idx] = __float2bfloat16(r);
  else    ((float*)out)[idx] = r;
}

// ---------------- O(N^2) conv, 16x16x32 MFMA, 2 queries/wave ----------------
// 8 waves/block, 512 blocks (2 blocks/CU exactly). Wave serves b0 and
// b0+4096: the f ds_reads, staging, barriers, and point/nuv loads are shared;
// only phase-1 math and the epilogue max/fma duplicate. 32 MFMAs/chunk on
// the ~19%-utilized matrix pipe.
__global__ __launch_bounds__(512) void conv_kernel(
    const float* __restrict__ pool, const float* __restrict__ fpad,
    float* __restrict__ cbuf) {
  __shared__ float  f_s[CHUNK_FLOATS];       // 17408 B padded f-tile
  __shared__ float4 hcA[WPB][2][4][33];      // 33792 B A-frags (2 queries)

  const int t = threadIdx.x;
  const int wv = t >> 6, lane = t & 63;
  const int b0 = blockIdx.x * WPB + wv;
  const int b1 = b0 + N_PTS / 2;
  const int kg  = lane >> 4;                 // k-group: k = 8*kg + i
  const int l15 = lane & 15;
  const int idx_fp = (kg < 2) ? (kg * 16 + l15) : 32;  // A-frag read slot

  // wave-uniform query data -> SGPRs (both queries)
  const float p0x = rfl(pool[OFF_POINTS + b0 * 3 + 0]);
  const float p0y = rfl(pool[OFF_POINTS + b0 * 3 + 1]);
  const float p0z = rfl(pool[OFF_POINTS + b0 * 3 + 2]);
  const float p1x = rfl(pool[OFF_POINTS + b1 * 3 + 0]);
  const float p1y = rfl(pool[OFF_POINTS + b1 * 3 + 1]);
  const float p1z = rfl(pool[OFF_POINTS + b1 * 3 + 2]);
  float nb0[9], nb1[9];
#pragma unroll
  for (int i = 0; i < 9; ++i) nb0[i] = rfl(pool[OFF_NUV + b0 * 9 + i]);
#pragma unroll
  for (int i = 0; i < 9; ++i) nb1[i] = rfl(pool[OFF_NUV + b1 * 9 + i]);
  float a1v[24], b1v[8];
#pragma unroll
  for (int i = 0; i < 24; ++i) a1v[i] = rfl(pool[OFF_A1 + i]);
#pragma unroll
  for (int i = 0; i < 8; ++i)  b1v[i] = rfl(pool[OFF_B1 + i]);

  // B fragments: B[k][h] = A2[h][k] (k<8), B2[h] (k==8), 0 (k>8). Shared.
  f16x8 bfrag[4];
#pragma unroll
  for (int ht = 0; ht < 4; ++ht) {
    const int h = 16 * ht + l15;
#pragma unroll
    for (int i = 0; i < 8; ++i) {
      float v = 0.f;
      if (kg == 0) v = pool[OFF_A2 + h * 8 + i];
      else if (kg == 1 && i == 0) v = pool[OFF_B2 + h];
      bfrag[ht][i] = (_Float16)v;
    }
  }

  // pre-zero kg1 words 1..3 and the zero slot (index 16..32 of each tile)
  if (lane < 17) {
    float4 z4; z4.x = 0.f; z4.y = 0.f; z4.z = 0.f; z4.w = 0.f;
#pragma unroll
    for (int jt = 0; jt < 4; ++jt) {
      hcA[wv][0][jt][16 + lane] = z4;
      hcA[wv][1][jt][16 + lane] = z4;
    }
  }

  const f32x4 kzero = {0.f, 0.f, 0.f, 0.f};
  float acc0[4] = {0.f, 0.f, 0.f, 0.f};
  float acc1[4] = {0.f, 0.f, 0.f, 0.f};

  for (int c = 0; c < NCHUNK; ++c) {
    // phase-1 inputs for this lane's n (shared by both queries)
    const int n = c * CHUNK + lane;
    const float px = pool[OFF_POINTS + n * 3 + 0];
    const float py = pool[OFF_POINTS + n * 3 + 1];
    const float pz = pool[OFF_POINTS + n * 3 + 2];
    const float nx = pool[OFF_NUV + n * 9 + 0];
    const float ny = pool[OFF_NUV + n * 9 + 1];
    const float nz = pool[OFF_NUV + n * 9 + 2];

    __syncthreads();                     // prior chunk's LDS reads done

    // async stage this chunk's padded f-tile (17408 B)
    {
      const glb_u32_t* src = (const glb_u32_t*)(fpad + c * CHUNK_FLOATS);
      lds_u32_t* dst = (lds_u32_t*)f_s;
      __builtin_amdgcn_global_load_lds(src + t * 4, dst + t * 4, 16, 0, 0);
      __builtin_amdgcn_global_load_lds(src + 2048 + t * 4, dst + 2048 + t * 4,
                                       16, 0, 0);
      if (wv == 0)
        __builtin_amdgcn_global_load_lds(src + 4096 + lane * 4,
                                         dst + 4096 + lane * 4, 16, 0, 0);
    }

    // phase 1, query 0
    {
      const float dx = px - p0x, dy = py - p0y, dz = pz - p0z;
      const float X0 = fmaf(nb0[0], dx, fmaf(nb0[1], dy, nb0[2] * dz));
      const float X1 = fmaf(nb0[3], dx, fmaf(nb0[4], dy, nb0[5] * dz));
      const float X2 = fmaf(nb0[6], dx, fmaf(nb0[7], dy, nb0[8] * dz));
      const float dn = fmaf(nb0[0], nx, fmaf(nb0[1], ny, nb0[2] * nz));
      const float dd = fmaf(dx, dx, fmaf(dy, dy, dz * dz));
      const float tt = 2.f - dn;
      const float w = __expf(-dd * tt * tt);
      float hc[8];
#pragma unroll
      for (int cc = 0; cc < 8; ++cc)
        hc[cc] = w * fmaxf(fmaf(X0, a1v[cc * 3 + 0],
                           fmaf(X1, a1v[cc * 3 + 1],
                           fmaf(X2, a1v[cc * 3 + 2], b1v[cc]))), 0.f);
      float4 lo;
      lo.x = __builtin_bit_cast(float, pk16(hc[0], hc[1]));
      lo.y = __builtin_bit_cast(float, pk16(hc[2], hc[3]));
      lo.z = __builtin_bit_cast(float, pk16(hc[4], hc[5]));
      lo.w = __builtin_bit_cast(float, pk16(hc[6], hc[7]));
      hcA[wv][0][lane >> 4][l15] = lo;
      ((float*)&hcA[wv][0][lane >> 4][16 + l15])[0] =
          __builtin_bit_cast(float, pk16(w, 0.f));
    }
    // phase 1, query 1
    {
      const float dx = px - p1x, dy = py - p1y, dz = pz - p1z;
      const float X0 = fmaf(nb1[0], dx, fmaf(nb1[1], dy, nb1[2] * dz));
      const float X1 = fmaf(nb1[3], dx, fmaf(nb1[4], dy, nb1[5] * dz));
      const float X2 = fmaf(nb1[6], dx, fmaf(nb1[7], dy, nb1[8] * dz));
      const float dn = fmaf(nb1[0], nx, fmaf(nb1[1], ny, nb1[2] * nz));
      const float dd = fmaf(dx, dx, fmaf(dy, dy, dz * dz));
      const float tt = 2.f - dn;
      const float w = __expf(-dd * tt * tt);
      float hc[8];
#pragma unroll
      for (int cc = 0; cc < 8; ++cc)
        hc[cc] = w * fmaxf(fmaf(X0, a1v[cc * 3 + 0],
                           fmaf(X1, a1v[cc * 3 + 1],
                           fmaf(X2, a1v[cc * 3 + 2], b1v[cc]))), 0.f);
      float4 lo;
      lo.x = __builtin_bit_cast(float, pk16(hc[0], hc[1]));
      lo.y = __builtin_bit_cast(float, pk16(hc[2], hc[3]));
      lo.z = __builtin_bit_cast(float, pk16(hc[4], hc[5]));
      lo.w = __builtin_bit_cast(float, pk16(hc[6], hc[7]));
      hcA[wv][1][lane >> 4][l15] = lo;
      ((float*)&hcA[wv][1][lane >> 4][16 + l15])[0] =
          __builtin_bit_cast(float, pk16(w, 0.f));
    }

    __syncthreads();                     // f_s (vmcnt drained) + hcA visible

    // phase 2: 4 jt x 4 ht tiles x 2 queries (f reads shared)
#pragma unroll
    for (int jt = 0; jt < 4; ++jt) {
      const f16x8 af0 = __builtin_bit_cast(f16x8, hcA[wv][0][jt][idx_fp]);
      const f16x8 af1 = __builtin_bit_cast(f16x8, hcA[wv][1][jt][idx_fp]);
      const int fbase = (16 * jt + kg * 4) * FS_STRIDE + l15;
#pragma unroll
      for (int ht = 0; ht < 4; ++ht) {
        const f32x4 D0 = __builtin_amdgcn_mfma_f32_16x16x32_f16(
            af0, bfrag[ht], kzero, 0, 0, 0);
        const f32x4 D1 = __builtin_amdgcn_mfma_f32_16x16x32_f16(
            af1, bfrag[ht], kzero, 0, 0, 0);
        const float* fb = &f_s[fbase + 16 * ht];
#pragma unroll
        for (int r = 0; r < 4; ++r) {
          const float fj = fb[r * FS_STRIDE];
          acc0[ht] = fmaf(fj, fmaxf(D0[r], 0.f), acc0[ht]);
          acc1[ht] = fmaf(fj, fmaxf(D1[r], 0.f), acc1[ht]);
        }
      }
    }
  }

  // reduce over the 4 lane quads; lanes 0..15 store both queries
#pragma unroll
  for (int ht = 0; ht < 4; ++ht) {
    acc0[ht] += __shfl_xor(acc0[ht], 16, 64);
    acc0[ht] += __shfl_xor(acc0[ht], 32, 64);
    acc1[ht] += __shfl_xor(acc1[ht], 16, 64);
    acc1[ht] += __shfl_xor(acc1[ht], 32, 64);
  }
  if (lane < 16) {
#pragma unroll
    for (int ht = 0; ht < 4; ++ht) {
      cbuf[b0 * 64 + 16 * ht + lane] = acc0[ht];
      cbuf[b1 * 64 + 16 * ht + lane] = acc1[ht];
    }
  }
}

extern "C" void kernel_launch(void* const* d_in, const int* in_sizes, int n_in,
                              void* d_out, int out_size, void* d_ws, size_t ws_size,
                              hipStream_t stream) {
  (void)in_sizes; (void)n_in; (void)out_size; (void)ws_size;
  const uint32_t* dref = (const uint32_t*)d_in[7];   // gn_in_w, all-ones

  float* pool   = (float*)d_ws;               // CVT_TOTAL fp32 inputs
  float* fbuf   = pool + CVT_TOTAL;           // N*64 (pre-GN f / f2-pre)
  float* fpad   = fbuf + N_PTS * 64;          // 128 * 4352 padded f tiles
  float* cbuf   = fpad + NCHUNK * CHUNK_FLOATS;  // N*64 conv output
  float* gstats = cbuf + N_PTS * 64;          // 16 (in:0-7, out:8-15)

  InPtrs ptrs;
  for (int i = 0; i < NSEG; ++i) ptrs.p[i] = d_in[i];

  prep_kernel<<<256, 256, 0, stream>>>(ptrs, pool, gstats);
  mlp_in_kernel<<<N_PTS / 4, 256, 0, stream>>>(pool, fbuf);
  gn_stats_kernel<<<64, 256, 0, stream>>>(fbuf, gstats);
  gn_apply_pad_kernel<<<N_PTS * 64 / 256, 256, 0, stream>>>(fbuf, gstats, pool,
                                                            fpad);
  conv_kernel<<<N_PTS / 2 / WPB, 512, 0, stream>>>(pool, fpad, cbuf);
  mlp_out_kernel<<<N_PTS / 4, 256, 0, stream>>>(cbuf, pool, fbuf);
  gn_stats_kernel<<<64, 256, 0, stream>>>(fbuf, gstats + 8);
  gn_apply_out_kernel<<<N_PTS * 64 / 256, 256, 0, stream>>>(
      fbuf, gstats + 8, pool, d_out, dref);
}